// Round 4
// baseline (161.512 us; speedup 1.0000x reference)
//
#include <hip/hip_runtime.h>
#include <hip/hip_bf16.h>
#include <stdint.h>

#define IN_FEATS 128
#define TWO_IN   256
#define HIDDEN   128

typedef __attribute__((ext_vector_type(8))) __bf16 bf16x8;
typedef __attribute__((ext_vector_type(8))) ushort u16x8;
typedef __attribute__((ext_vector_type(4))) float f32x4;

__device__ __forceinline__ float bf_lo(uint32_t u) { return __uint_as_float(u << 16); }
__device__ __forceinline__ float bf_hi(uint32_t u) { return __uint_as_float(u & 0xffff0000u); }
__device__ __forceinline__ ushort f2bf(float f) {
  uint32_t u = __float_as_uint(f);
  uint32_t r = (u + 0x7fffu + ((u >> 16) & 1u)) >> 16;  // RNE
  return (ushort)r;
}

// ---------------- prep: W1 -> Bm[n][k] bf16 (n<128: W1a, n>=128: W1b) ----------------
__global__ void cvt_w1_kernel(const float* __restrict__ W1, ushort* __restrict__ Bm) {
  int t = blockIdx.x * blockDim.x + threadIdx.x;
  if (t >= TWO_IN * IN_FEATS) return;
  int n = t >> 7, k = t & 127;
  float v = (n < HIDDEN) ? W1[n * TWO_IN + k]
                         : W1[(n - HIDDEN) * TWO_IN + IN_FEATS + k];
  Bm[t] = f2bf(v);
}

// ---------------- fused GEMM: P[M][256] = bf16(h)[M][128] @ Bm[256][128]^T + 0.5*b1 ----
// 128x256 tile, 1024 threads = 16 waves (4 row-strips x 4 col-strips), 4 waves/SIMD.
__global__ __launch_bounds__(1024)
void gemm_fused_kernel(const float* __restrict__ h, const ushort* __restrict__ Bm,
                       const float* __restrict__ b1, ushort* __restrict__ P, int M) {
  __shared__ __align__(16) char ldsraw[98304];   // A 32KB | B 64KB; reused as out-stage 66KB
  const int tid  = threadIdx.x;      // 0..1023
  const int lane = tid & 63;
  const int w    = tid >> 6;         // 0..15
  const int m0   = blockIdx.x * 128;

  char* ldsA = ldsraw;                      // 128 rows x 256B (swizzled)
  char* ldsB = ldsraw + 32768;              // 256 rows x 256B (swizzled)

  // --- stage B via global_load_lds (source pre-swizzled, LDS dest linear) ---
  const char* Bsrc = (const char*)Bm;
  #pragma unroll
  for (int it = 0; it < 4; ++it) {
    int idx = it * 1024 + tid;              // 16B chunk id, 0..4095
    int row = idx >> 4;                     // 0..255
    int scb = ((idx & 15) << 4) ^ ((row & 7) << 4);
    int goff = row * 256 + scb;
    int ldsoff = it * 16384 + w * 1024;     // wave-uniform; HW adds lane*16
    __builtin_amdgcn_global_load_lds(
        (const __attribute__((address_space(1))) void*)(Bsrc + goff),
        (__attribute__((address_space(3))) void*)(ldsB + ldsoff), 16, 0, 0);
  }

  // --- stage A: h fp32 -> bf16, reg-staged, swizzled ds_write_b128 ---
  #pragma unroll
  for (int it = 0; it < 2; ++it) {
    int idx = it * 1024 + tid;              // 0..2047 (128 rows x 16 chunks)
    int row = idx >> 4;
    int c   = idx & 15;                     // chunk of 8 floats
    int grow = m0 + row;
    float4 v0 = {0, 0, 0, 0}, v1 = {0, 0, 0, 0};
    if (grow < M) {
      const float* src = h + (size_t)grow * IN_FEATS + c * 8;
      v0 = *(const float4*)(src);
      v1 = *(const float4*)(src + 4);
    }
    u16x8 o;
    o[0] = f2bf(v0.x); o[1] = f2bf(v0.y); o[2] = f2bf(v0.z); o[3] = f2bf(v0.w);
    o[4] = f2bf(v1.x); o[5] = f2bf(v1.y); o[6] = f2bf(v1.z); o[7] = f2bf(v1.w);
    *(u16x8*)(ldsA + row * 256 + ((c * 16) ^ ((row & 7) << 4))) = o;
  }
  __syncthreads();

  const int wr = w >> 2, wc = w & 3;        // wave tile: 32 rows x 64 cols
  f32x4 acc[2][4] = {};

  #pragma unroll
  for (int kk = 0; kk < 4; ++kk) {
    bf16x8 af[2], bfr[4];
    const int kb = kk * 64 + ((lane >> 4) << 4);
    #pragma unroll
    for (int m = 0; m < 2; ++m) {
      int row = wr * 32 + m * 16 + (lane & 15);
      af[m] = *(const bf16x8*)(ldsA + row * 256 + (kb ^ ((row & 7) << 4)));
    }
    #pragma unroll
    for (int n = 0; n < 4; ++n) {
      int row = wc * 64 + n * 16 + (lane & 15);
      bfr[n] = *(const bf16x8*)(ldsB + row * 256 + (kb ^ ((row & 7) << 4)));
    }
    #pragma unroll
    for (int m = 0; m < 2; ++m)
      #pragma unroll
      for (int n = 0; n < 4; ++n)
        acc[m][n] = __builtin_amdgcn_mfma_f32_16x16x32_bf16(af[m], bfr[n], acc[m][n], 0, 0, 0);
  }

  // bias fold: P += 0.5*b1[col & 127] (src-half + dst-half reconstruct b1)
  float bias[4];
  #pragma unroll
  for (int n = 0; n < 4; ++n) {
    int col = wc * 64 + n * 16 + (lane & 15);
    bias[n] = 0.5f * b1[col & 127];
  }

  __syncthreads();
  ushort* outLds = (ushort*)ldsraw;         // 128 rows x 264 shorts (66KB)
  #pragma unroll
  for (int m = 0; m < 2; ++m) {
    #pragma unroll
    for (int n = 0; n < 4; ++n) {
      int col = wc * 64 + n * 16 + (lane & 15);
      #pragma unroll
      for (int r = 0; r < 4; ++r) {
        int row = wr * 32 + m * 16 + ((lane >> 4) << 2) + r;
        outLds[row * 264 + col] = f2bf(acc[m][n][r] + bias[n]);
      }
    }
  }
  __syncthreads();
  const int mleft = M - m0;
  #pragma unroll
  for (int it = 0; it < 4; ++it) {
    int idx = it * 1024 + tid;              // 16B chunk, 0..4095
    int row = idx >> 5;                     // 32 chunks per 512B row
    int c   = idx & 31;
    if (row < mleft)
      *(u16x8*)((char*)P + (size_t)(m0 + row) * 512 + c * 16) =
          *(const u16x8*)(outLds + row * 264 + c * 8);
  }
}

// ---------------- edge phase: 16 lanes/edge, dual-quad (8 edges) per iteration ----------------
__global__ __launch_bounds__(256)
void edge_kernel(const int* __restrict__ src, const int* __restrict__ dst,
                 const ushort* __restrict__ P,
                 const float* __restrict__ W2, const float* __restrict__ b2,
                 float* __restrict__ out, int nE, int qpw) {
  const int lane = threadIdx.x & 63;
  const int t = lane & 15;          // sublane: feats [t*8, t*8+8)
  const int g = lane >> 4;          // edge slot within quad
  const int wid = blockIdx.x * (blockDim.x >> 6) + (threadIdx.x >> 6);
  const float4 w2a = ((const float4*)W2)[2 * t];
  const float4 w2b = ((const float4*)W2)[2 * t + 1];
  const float b2s = *b2;

  const int Q = (nE + 3) >> 2;
  const int q0 = wid * qpw;
  const int qe = min(q0 + qpw, Q);
  const int to8 = t * 8;

  for (int q = q0; q < qe; q += 2) {
    int e0 = q * 4 + g;
    int e1 = e0 + 4;
    int ec0 = min(e0, nE - 1);
    int ec1 = min(e1, nE - 1);
    // all index loads first
    int s0 = src[ec0], d0 = dst[ec0];
    int s1 = src[ec1], d1 = dst[ec1];
    // all gathers issued before any consumption
    uint4 pa0 = *(const uint4*)(P + (size_t)s0 * 256 + to8);
    uint4 pb0 = *(const uint4*)(P + (size_t)d0 * 256 + 128 + to8);
    uint4 pa1 = *(const uint4*)(P + (size_t)s1 * 256 + to8);
    uint4 pb1 = *(const uint4*)(P + (size_t)d1 * 256 + 128 + to8);

    float a0;
    a0 = fmaxf(bf_lo(pa0.x) + bf_lo(pb0.x), 0.0f) * w2a.x;
    a0 = fmaf(fmaxf(bf_hi(pa0.x) + bf_hi(pb0.x), 0.0f), w2a.y, a0);
    a0 = fmaf(fmaxf(bf_lo(pa0.y) + bf_lo(pb0.y), 0.0f), w2a.z, a0);
    a0 = fmaf(fmaxf(bf_hi(pa0.y) + bf_hi(pb0.y), 0.0f), w2a.w, a0);
    a0 = fmaf(fmaxf(bf_lo(pa0.z) + bf_lo(pb0.z), 0.0f), w2b.x, a0);
    a0 = fmaf(fmaxf(bf_hi(pa0.z) + bf_hi(pb0.z), 0.0f), w2b.y, a0);
    a0 = fmaf(fmaxf(bf_lo(pa0.w) + bf_lo(pb0.w), 0.0f), w2b.z, a0);
    a0 = fmaf(fmaxf(bf_hi(pa0.w) + bf_hi(pb0.w), 0.0f), w2b.w, a0);

    float a1;
    a1 = fmaxf(bf_lo(pa1.x) + bf_lo(pb1.x), 0.0f) * w2a.x;
    a1 = fmaf(fmaxf(bf_hi(pa1.x) + bf_hi(pb1.x), 0.0f), w2a.y, a1);
    a1 = fmaf(fmaxf(bf_lo(pa1.y) + bf_lo(pb1.y), 0.0f), w2a.z, a1);
    a1 = fmaf(fmaxf(bf_hi(pa1.y) + bf_hi(pb1.y), 0.0f), w2a.w, a1);
    a1 = fmaf(fmaxf(bf_lo(pa1.z) + bf_lo(pb1.z), 0.0f), w2b.x, a1);
    a1 = fmaf(fmaxf(bf_hi(pa1.z) + bf_hi(pb1.z), 0.0f), w2b.y, a1);
    a1 = fmaf(fmaxf(bf_lo(pa1.w) + bf_lo(pb1.w), 0.0f), w2b.z, a1);
    a1 = fmaf(fmaxf(bf_hi(pa1.w) + bf_hi(pb1.w), 0.0f), w2b.w, a1);

    a0 += __shfl_xor(a0, 8);
    a0 += __shfl_xor(a0, 4);
    a0 += __shfl_xor(a0, 2);
    a0 += __shfl_xor(a0, 1);
    a1 += __shfl_xor(a1, 8);
    a1 += __shfl_xor(a1, 4);
    a1 += __shfl_xor(a1, 2);
    a1 += __shfl_xor(a1, 1);

    if (t == 0 && e0 < nE) out[e0] = 1.0f / (1.0f + __expf(-(a0 + b2s)));
    if (t == 0 && (q + 1) < qe && e1 < nE) out[e1] = 1.0f / (1.0f + __expf(-(a1 + b2s)));
  }
}

extern "C" void kernel_launch(void* const* d_in, const int* in_sizes, int n_in,
                              void* d_out, int out_size, void* d_ws, size_t ws_size,
                              hipStream_t stream) {
  const int*   src = (const int*)d_in[0];
  const int*   dst = (const int*)d_in[1];
  const float* h   = (const float*)d_in[2];
  const float* W1  = (const float*)d_in[3];
  const float* b1  = (const float*)d_in[4];
  const float* W2  = (const float*)d_in[5];
  const float* b2  = (const float*)d_in[6];
  float* out = (float*)d_out;
  const int nE = in_sizes[0];
  const int nN = in_sizes[2] / IN_FEATS;
  const int nBlocksM = (nN + 127) / 128;

  char* ws = (char*)d_ws;
  ushort* Bm = (ushort*)ws;                       // 64KB
  ushort* P  = (ushort*)(ws + 65536);             // nN*512 B  (~51.2MB)

  hipLaunchKernelGGL(cvt_w1_kernel, dim3((TWO_IN * IN_FEATS + 255) / 256), dim3(256), 0, stream, W1, Bm);
  hipLaunchKernelGGL(gemm_fused_kernel, dim3(nBlocksM), dim3(1024), 0, stream, h, Bm, b1, P, nN);

  const int EDGE_BLOCKS = 2048;                   // 8 blocks/CU at 256 thr
  const int nw = EDGE_BLOCKS * 4;
  const int Q = (nE + 3) / 4;
  const int qpw = (Q + nw - 1) / nw;
  hipLaunchKernelGGL(edge_kernel, dim3(EDGE_BLOCKS), dim3(256), 0, stream, src, dst, P, W2, b2, out, nE, qpw);
}

// Round 6
// 154.552 us; speedup vs baseline: 1.0450x; 1.0450x over previous
//
#include <hip/hip_runtime.h>
#include <hip/hip_bf16.h>
#include <stdint.h>

#define IN_FEATS 128
#define TWO_IN   256
#define HIDDEN   128
#define TILE_M   64
#define GEMM_BLOCKS 256

typedef __attribute__((ext_vector_type(8))) __bf16 bf16x8;
typedef __attribute__((ext_vector_type(8))) ushort u16x8;
typedef __attribute__((ext_vector_type(4))) float f32x4;

__device__ __forceinline__ float bf_lo(uint32_t u) { return __uint_as_float(u << 16); }
__device__ __forceinline__ float bf_hi(uint32_t u) { return __uint_as_float(u & 0xffff0000u); }
__device__ __forceinline__ ushort f2bf(float f) {
  uint32_t u = __float_as_uint(f);
  uint32_t r = (u + 0x7fffu + ((u >> 16) & 1u)) >> 16;  // RNE
  return (ushort)r;
}

// ---------------- prep: W1 -> Bm[n][k] bf16 (n<128: W1a, n>=128: W1b) ----------------
__global__ void cvt_w1_kernel(const float* __restrict__ W1, ushort* __restrict__ Bm) {
  int t = blockIdx.x * blockDim.x + threadIdx.x;
  if (t >= TWO_IN * IN_FEATS) return;
  int n = t >> 7, k = t & 127;
  float v = (n < HIDDEN) ? W1[n * TWO_IN + k]
                         : W1[(n - HIDDEN) * TWO_IN + IN_FEATS + k];
  Bm[t] = f2bf(v);
}

// ---------------- persistent pipelined GEMM ----------------
// P[M][256] = bf16(h)[M][128] @ Bm[256][128]^T + 0.5*b1
// grid = 256 persistent blocks, 512 threads (8 waves, 2x4 wave grid).
// Per block: B staged ONCE (64KB, global_load_lds in prologue only — proven context),
// then loop over m-tiles (64 rows) with A double-buffer + reg-prefetch of tile t+1
// issued before tile t's compute/epilogue. Single-block residency (130KB LDS),
// all in-loop sync is plain ds_write/ds_read + __syncthreads (2 barriers/iter).
__global__ __launch_bounds__(512)
void gemm_pipe_kernel(const float* __restrict__ h, const ushort* __restrict__ Bm,
                      const float* __restrict__ b1, ushort* __restrict__ P,
                      int M, int nTiles) {
  __shared__ __align__(16) char ldsraw[132096];
  // layout: A0 16KB | A1 16KB | outLds 33792B | B 64KB   (disjoint, no aliasing)
  char* ldsA0   = ldsraw;
  char* ldsA1   = ldsraw + 16384;
  ushort* outLds = (ushort*)(ldsraw + 32768);       // 64 rows x 264 shorts
  char* ldsB    = ldsraw + 66560;

  const int tid  = threadIdx.x;      // 0..511
  const int lane = tid & 63;
  const int w    = tid >> 6;         // 0..7

  // --- stage B once via global_load_lds (source pre-swizzled, LDS dest linear) ---
  const char* Bsrc = (const char*)Bm;
  #pragma unroll
  for (int it = 0; it < 8; ++it) {
    int idx = it * 512 + tid;               // 16B chunk id, 0..4095
    int row = idx >> 4;                     // 0..255
    int scb = ((idx & 15) << 4) ^ ((row & 7) << 4);
    int goff = row * 256 + scb;
    int ldsoff = it * 8192 + w * 1024;      // wave-uniform; HW adds lane*16
    __builtin_amdgcn_global_load_lds(
        (const __attribute__((address_space(1))) void*)(Bsrc + goff),
        (__attribute__((address_space(3))) void*)(ldsB + ldsoff), 16, 0, 0);
  }

  // --- stage A for first tile into A0 ---
  {
    int t0 = blockIdx.x;
    int m0 = t0 * TILE_M;
    #pragma unroll
    for (int k = 0; k < 2; ++k) {
      int idx = k * 512 + tid;              // 0..1023 = 64 rows x 16 chunks
      int row = idx >> 4;
      int c   = idx & 15;
      int grow = m0 + row;
      float4 v0 = {0, 0, 0, 0}, v1 = {0, 0, 0, 0};
      if (grow < M) {
        const float* src = h + (size_t)grow * IN_FEATS + c * 8;
        v0 = *(const float4*)(src);
        v1 = *(const float4*)(src + 4);
      }
      u16x8 o;
      o[0] = f2bf(v0.x); o[1] = f2bf(v0.y); o[2] = f2bf(v0.z); o[3] = f2bf(v0.w);
      o[4] = f2bf(v1.x); o[5] = f2bf(v1.y); o[6] = f2bf(v1.z); o[7] = f2bf(v1.w);
      *(u16x8*)(ldsA0 + row * 256 + ((c * 16) ^ ((row & 7) << 4))) = o;
    }
  }
  __syncthreads();   // B + A0 staged (compiler drains vmcnt+lgkm here — proven prologue)

  const int wr = w >> 2, wc = w & 3;        // wave tile: 32 rows x 64 cols

  // bias fold: P += 0.5*b1[col & 127] (src-half + dst-half reconstruct b1)
  float bias[4];
  #pragma unroll
  for (int n = 0; n < 4; ++n) {
    int col = wc * 64 + n * 16 + (lane & 15);
    bias[n] = 0.5f * b1[col & 127];
  }

  int cur = 0;
  for (int t = blockIdx.x; t < nTiles; t += GEMM_BLOCKS) {
    const int m0 = t * TILE_M;
    const int tn = t + GEMM_BLOCKS;
    const bool pf = (tn < nTiles);
    char* ldsAcur = cur ? ldsA1 : ldsA0;
    char* ldsAnxt = cur ? ldsA0 : ldsA1;

    // --- issue prefetch loads for tile t+GEMM_BLOCKS (fp32 -> regs, no wait) ---
    float4 p0[2], p1[2];
    int prow[2], pc[2];
    #pragma unroll
    for (int k = 0; k < 2; ++k) {
      int idx = k * 512 + tid;
      prow[k] = idx >> 4;
      pc[k]   = idx & 15;
      p0[k] = (float4){0, 0, 0, 0};
      p1[k] = (float4){0, 0, 0, 0};
      if (pf) {
        int grow = tn * TILE_M + prow[k];
        if (grow < M) {
          const float* src = h + (size_t)grow * IN_FEATS + pc[k] * 8;
          p0[k] = *(const float4*)(src);
          p1[k] = *(const float4*)(src + 4);
        }
      }
    }

    // --- MFMA on A[cur], B ---
    f32x4 acc[2][4] = {};
    #pragma unroll
    for (int kk = 0; kk < 4; ++kk) {
      bf16x8 af[2], bfr[4];
      const int kb = kk * 64 + ((lane >> 4) << 4);
      #pragma unroll
      for (int m = 0; m < 2; ++m) {
        int row = wr * 32 + m * 16 + (lane & 15);
        af[m] = *(const bf16x8*)(ldsAcur + row * 256 + (kb ^ ((row & 7) << 4)));
      }
      #pragma unroll
      for (int n = 0; n < 4; ++n) {
        int row = wc * 64 + n * 16 + (lane & 15);
        bfr[n] = *(const bf16x8*)(ldsB + row * 256 + (kb ^ ((row & 7) << 4)));
      }
      #pragma unroll
      for (int m = 0; m < 2; ++m)
        #pragma unroll
        for (int n = 0; n < 4; ++n)
          acc[m][n] = __builtin_amdgcn_mfma_f32_16x16x32_bf16(af[m], bfr[n], acc[m][n], 0, 0, 0);
    }

    __syncthreads();  // B1: prior iter's store-phase finished reading outLds

    // --- acc + bias -> outLds (bf16) ---
    #pragma unroll
    for (int m = 0; m < 2; ++m) {
      #pragma unroll
      for (int n = 0; n < 4; ++n) {
        int col = wc * 64 + n * 16 + (lane & 15);
        #pragma unroll
        for (int r = 0; r < 4; ++r) {
          int row = wr * 32 + m * 16 + ((lane >> 4) << 2) + r;
          outLds[row * 264 + col] = f2bf(acc[m][n][r] + bias[n]);
        }
      }
    }

    // --- convert prefetched A and write to the other buffer ---
    if (pf) {
      #pragma unroll
      for (int k = 0; k < 2; ++k) {
        u16x8 o;
        o[0] = f2bf(p0[k].x); o[1] = f2bf(p0[k].y); o[2] = f2bf(p0[k].z); o[3] = f2bf(p0[k].w);
        o[4] = f2bf(p1[k].x); o[5] = f2bf(p1[k].y); o[6] = f2bf(p1[k].z); o[7] = f2bf(p1[k].w);
        *(u16x8*)(ldsAnxt + prow[k] * 256 + ((pc[k] * 16) ^ ((prow[k] & 7) << 4))) = o;
      }
    }

    __syncthreads();  // B2: outLds + A[next] writes visible

    // --- outLds -> P global stores (tile t) ---
    const int mleft = M - m0;
    #pragma unroll
    for (int it = 0; it < 4; ++it) {
      int idx = it * 512 + tid;             // 16B chunk, 0..2047
      int row = idx >> 5;                   // 32 chunks per 512B row
      int c   = idx & 31;
      if (row < mleft)
        *(u16x8*)((char*)P + (size_t)(m0 + row) * 512 + c * 16) =
            *(const u16x8*)(outLds + row * 264 + c * 8);
    }
    cur ^= 1;
  }
}

// ---------------- edge phase: 16 lanes/edge, 4 edges/wave (R2 measured-best form) ----
__global__ __launch_bounds__(256)
void edge_kernel(const int* __restrict__ src, const int* __restrict__ dst,
                 const ushort* __restrict__ P,
                 const float* __restrict__ W2, const float* __restrict__ b2,
                 float* __restrict__ out, int nE) {
  const int lane = threadIdx.x & 63;
  const int t = lane & 15;          // sublane: feats [t*8, t*8+8)
  const int g = lane >> 4;          // edge slot within wave
  const int wid = blockIdx.x * (blockDim.x >> 6) + (threadIdx.x >> 6);
  const int nw  = gridDim.x * (blockDim.x >> 6);
  const float4 w2a = ((const float4*)W2)[2 * t];
  const float4 w2b = ((const float4*)W2)[2 * t + 1];
  const float b2s = *b2;

  #pragma unroll 2
  for (int e0 = wid * 4; e0 < nE; e0 += nw * 4) {
    int e = e0 + g;
    bool valid = e < nE;
    int ec = valid ? e : nE - 1;
    int s = src[ec], d = dst[ec];
    uint4 pa = *(const uint4*)(P + (size_t)s * 256 + t * 8);
    uint4 pb = *(const uint4*)(P + (size_t)d * 256 + 128 + t * 8);
    float acc;
    acc = fmaxf(bf_lo(pa.x) + bf_lo(pb.x), 0.0f) * w2a.x;
    acc = fmaf(fmaxf(bf_hi(pa.x) + bf_hi(pb.x), 0.0f), w2a.y, acc);
    acc = fmaf(fmaxf(bf_lo(pa.y) + bf_lo(pb.y), 0.0f), w2a.z, acc);
    acc = fmaf(fmaxf(bf_hi(pa.y) + bf_hi(pb.y), 0.0f), w2a.w, acc);
    acc = fmaf(fmaxf(bf_lo(pa.z) + bf_lo(pb.z), 0.0f), w2b.x, acc);
    acc = fmaf(fmaxf(bf_hi(pa.z) + bf_hi(pb.z), 0.0f), w2b.y, acc);
    acc = fmaf(fmaxf(bf_lo(pa.w) + bf_lo(pb.w), 0.0f), w2b.z, acc);
    acc = fmaf(fmaxf(bf_hi(pa.w) + bf_hi(pb.w), 0.0f), w2b.w, acc);
    acc += __shfl_xor(acc, 8);
    acc += __shfl_xor(acc, 4);
    acc += __shfl_xor(acc, 2);
    acc += __shfl_xor(acc, 1);
    if (t == 0 && valid) out[e] = 1.0f / (1.0f + __expf(-(acc + b2s)));
  }
}

extern "C" void kernel_launch(void* const* d_in, const int* in_sizes, int n_in,
                              void* d_out, int out_size, void* d_ws, size_t ws_size,
                              hipStream_t stream) {
  const int*   src = (const int*)d_in[0];
  const int*   dst = (const int*)d_in[1];
  const float* h   = (const float*)d_in[2];
  const float* W1  = (const float*)d_in[3];
  const float* b1  = (const float*)d_in[4];
  const float* W2  = (const float*)d_in[5];
  const float* b2  = (const float*)d_in[6];
  float* out = (float*)d_out;
  const int nE = in_sizes[0];
  const int nN = in_sizes[2] / IN_FEATS;
  const int nTiles = (nN + TILE_M - 1) / TILE_M;

  char* ws = (char*)d_ws;
  ushort* Bm = (ushort*)ws;                       // 64KB
  ushort* P  = (ushort*)(ws + 65536);             // nN*512 B  (~51.2MB)

  hipLaunchKernelGGL(cvt_w1_kernel, dim3((TWO_IN * IN_FEATS + 255) / 256), dim3(256), 0, stream, W1, Bm);
  hipLaunchKernelGGL(gemm_pipe_kernel, dim3(GEMM_BLOCKS), dim3(512), 0, stream, h, Bm, b1, P, nN, nTiles);
  hipLaunchKernelGGL(edge_kernel, dim3(4096), dim3(256), 0, stream, src, dst, P, W2, b2, out, nE);
}

// Round 8
// 152.831 us; speedup vs baseline: 1.0568x; 1.0113x over previous
//
#include <hip/hip_runtime.h>
#include <hip/hip_bf16.h>
#include <stdint.h>

#define IN_FEATS 128
#define TWO_IN   256
#define HIDDEN   128
#define TILE_M   64
#define GEMM_BLOCKS 256

typedef __attribute__((ext_vector_type(8))) __bf16 bf16x8;
typedef __attribute__((ext_vector_type(8))) ushort u16x8;
typedef __attribute__((ext_vector_type(4))) float f32x4;

__device__ __forceinline__ float bf_lo(uint32_t u) { return __uint_as_float(u << 16); }
__device__ __forceinline__ float bf_hi(uint32_t u) { return __uint_as_float(u & 0xffff0000u); }
__device__ __forceinline__ ushort f2bf(float f) {
  uint32_t u = __float_as_uint(f);
  uint32_t r = (u + 0x7fffu + ((u >> 16) & 1u)) >> 16;  // RNE
  return (ushort)r;
}

// ---------------- persistent pipelined GEMM, W1-conversion fused ----------------
// P[M][256] = bf16(h)[M][128] @ bf16(W1cat)[256][128]^T + 0.5*b1
// grid = 256 persistent blocks x 1024 threads (16 waves, 4x4 wave grid; 4 waves/SIMD).
// Prologue: W1 fp32 -> swizzled LDS B (reg-staged, per block; L2-multicast) and
// first A tile. Loop: A double-buffer, reg-prefetch of tile t+256 issued before
// MFMA/epilogue of tile t. 129KB LDS -> 1 block/CU (single-block residency, no
// multi-block race surface), 2 barriers/iter (R6-proven structure).
__global__ __launch_bounds__(1024)
void gemm_pipe_kernel(const float* __restrict__ h, const float* __restrict__ W1,
                      const float* __restrict__ b1, ushort* __restrict__ P,
                      int M, int nTiles) {
  __shared__ __align__(16) char ldsraw[132096];
  // layout: A0 16KB | A1 16KB | outLds 33792B | B 64KB   (disjoint, no aliasing)
  char* ldsA0    = ldsraw;
  char* ldsA1    = ldsraw + 16384;
  ushort* outLds = (ushort*)(ldsraw + 32768);       // 64 rows x 264 shorts
  char* ldsB     = ldsraw + 66560;

  const int tid  = threadIdx.x;      // 0..1023
  const int lane = tid & 63;
  const int w    = tid >> 6;         // 0..15

  // --- stage B: W1 fp32 -> bf16, swizzled ds_write (fused cvt_w1) ---
  // Bm[n][k] = n<128 ? W1[n][k] : W1[n-128][128+k]
  #pragma unroll
  for (int it = 0; it < 4; ++it) {
    int idx = it * 1024 + tid;              // 8-elem chunk id, 0..4095
    int row = idx >> 4;                     // 0..255
    int c   = idx & 15;                     // chunk of 8 floats
    const float* srcp = (row < HIDDEN) ? (W1 + row * TWO_IN + c * 8)
                                       : (W1 + (row - HIDDEN) * TWO_IN + IN_FEATS + c * 8);
    float4 v0 = *(const float4*)(srcp);
    float4 v1 = *(const float4*)(srcp + 4);
    u16x8 o;
    o[0] = f2bf(v0.x); o[1] = f2bf(v0.y); o[2] = f2bf(v0.z); o[3] = f2bf(v0.w);
    o[4] = f2bf(v1.x); o[5] = f2bf(v1.y); o[6] = f2bf(v1.z); o[7] = f2bf(v1.w);
    *(u16x8*)(ldsB + row * 256 + ((c * 16) ^ ((row & 7) << 4))) = o;
  }

  // --- stage A for first tile into A0 ---
  {
    int m0 = blockIdx.x * TILE_M;
    int row = tid >> 4;                     // 64 rows x 16 chunks = 1024
    int c   = tid & 15;
    int grow = m0 + row;
    float4 v0 = {0, 0, 0, 0}, v1 = {0, 0, 0, 0};
    if (grow < M) {
      const float* src = h + (size_t)grow * IN_FEATS + c * 8;
      v0 = *(const float4*)(src);
      v1 = *(const float4*)(src + 4);
    }
    u16x8 o;
    o[0] = f2bf(v0.x); o[1] = f2bf(v0.y); o[2] = f2bf(v0.z); o[3] = f2bf(v0.w);
    o[4] = f2bf(v1.x); o[5] = f2bf(v1.y); o[6] = f2bf(v1.z); o[7] = f2bf(v1.w);
    *(u16x8*)(ldsA0 + row * 256 + ((c * 16) ^ ((row & 7) << 4))) = o;
  }
  __syncthreads();   // B + A0 staged

  const int wr = w >> 2, wc = w & 3;        // wave tile: 16 rows x 64 cols

  // bias fold: P += 0.5*b1[col & 127] (src-half + dst-half reconstruct b1)
  float bias[4];
  #pragma unroll
  for (int n = 0; n < 4; ++n) {
    int col = wc * 64 + n * 16 + (lane & 15);
    bias[n] = 0.5f * b1[col & 127];
  }

  int cur = 0;
  for (int t = blockIdx.x; t < nTiles; t += GEMM_BLOCKS) {
    const int m0 = t * TILE_M;
    const int tn = t + GEMM_BLOCKS;
    const bool pf = (tn < nTiles);
    char* ldsAcur = cur ? ldsA1 : ldsA0;
    char* ldsAnxt = cur ? ldsA0 : ldsA1;

    // --- issue prefetch loads for tile t+GEMM_BLOCKS (fp32 -> regs, no wait) ---
    const int prow = tid >> 4;
    const int pc   = tid & 15;
    float4 p0 = {0, 0, 0, 0}, p1 = {0, 0, 0, 0};
    if (pf) {
      int grow = tn * TILE_M + prow;
      if (grow < M) {
        const float* src = h + (size_t)grow * IN_FEATS + pc * 8;
        p0 = *(const float4*)(src);
        p1 = *(const float4*)(src + 4);
      }
    }

    // --- MFMA on A[cur], B ---
    f32x4 acc[4] = {};
    #pragma unroll
    for (int kk = 0; kk < 4; ++kk) {
      bf16x8 af, bfr[4];
      const int kb = kk * 64 + ((lane >> 4) << 4);
      {
        int row = wr * 16 + (lane & 15);
        af = *(const bf16x8*)(ldsAcur + row * 256 + (kb ^ ((row & 7) << 4)));
      }
      #pragma unroll
      for (int n = 0; n < 4; ++n) {
        int row = wc * 64 + n * 16 + (lane & 15);
        bfr[n] = *(const bf16x8*)(ldsB + row * 256 + (kb ^ ((row & 7) << 4)));
      }
      #pragma unroll
      for (int n = 0; n < 4; ++n)
        acc[n] = __builtin_amdgcn_mfma_f32_16x16x32_bf16(af, bfr[n], acc[n], 0, 0, 0);
    }

    __syncthreads();  // B1: prior iter's store-phase finished reading outLds

    // --- acc + bias -> outLds (bf16) ---
    #pragma unroll
    for (int n = 0; n < 4; ++n) {
      int col = wc * 64 + n * 16 + (lane & 15);
      #pragma unroll
      for (int r = 0; r < 4; ++r) {
        int row = wr * 16 + ((lane >> 4) << 2) + r;
        outLds[row * 264 + col] = f2bf(acc[n][r] + bias[n]);
      }
    }

    // --- convert prefetched A and write to the other buffer ---
    if (pf) {
      u16x8 o;
      o[0] = f2bf(p0.x); o[1] = f2bf(p0.y); o[2] = f2bf(p0.z); o[3] = f2bf(p0.w);
      o[4] = f2bf(p1.x); o[5] = f2bf(p1.y); o[6] = f2bf(p1.z); o[7] = f2bf(p1.w);
      *(u16x8*)(ldsAnxt + prow * 256 + ((pc * 16) ^ ((prow & 7) << 4))) = o;
    }

    __syncthreads();  // B2: outLds + A[next] writes visible

    // --- outLds -> P global stores (tile t) ---
    const int mleft = M - m0;
    #pragma unroll
    for (int it = 0; it < 2; ++it) {
      int idx = it * 1024 + tid;            // 16B chunk, 0..2047
      int row = idx >> 5;                   // 32 chunks per 512B row
      int c   = idx & 31;
      if (row < mleft)
        *(u16x8*)((char*)P + (size_t)(m0 + row) * 512 + c * 16) =
            *(const u16x8*)(outLds + row * 264 + c * 8);
    }
    cur ^= 1;
  }
}

// ---------------- edge phase: 16 lanes/edge, 4 edges/wave (R2 measured-best form) ----
__global__ __launch_bounds__(256)
void edge_kernel(const int* __restrict__ src, const int* __restrict__ dst,
                 const ushort* __restrict__ P,
                 const float* __restrict__ W2, const float* __restrict__ b2,
                 float* __restrict__ out, int nE) {
  const int lane = threadIdx.x & 63;
  const int t = lane & 15;          // sublane: feats [t*8, t*8+8)
  const int g = lane >> 4;          // edge slot within wave
  const int wid = blockIdx.x * (blockDim.x >> 6) + (threadIdx.x >> 6);
  const int nw  = gridDim.x * (blockDim.x >> 6);
  const float4 w2a = ((const float4*)W2)[2 * t];
  const float4 w2b = ((const float4*)W2)[2 * t + 1];
  const float b2s = *b2;

  #pragma unroll 2
  for (int e0 = wid * 4; e0 < nE; e0 += nw * 4) {
    int e = e0 + g;
    bool valid = e < nE;
    int ec = valid ? e : nE - 1;
    int s = src[ec], d = dst[ec];
    uint4 pa = *(const uint4*)(P + (size_t)s * 256 + t * 8);
    uint4 pb = *(const uint4*)(P + (size_t)d * 256 + 128 + t * 8);
    float acc;
    acc = fmaxf(bf_lo(pa.x) + bf_lo(pb.x), 0.0f) * w2a.x;
    acc = fmaf(fmaxf(bf_hi(pa.x) + bf_hi(pb.x), 0.0f), w2a.y, acc);
    acc = fmaf(fmaxf(bf_lo(pa.y) + bf_lo(pb.y), 0.0f), w2a.z, acc);
    acc = fmaf(fmaxf(bf_hi(pa.y) + bf_hi(pb.y), 0.0f), w2a.w, acc);
    acc = fmaf(fmaxf(bf_lo(pa.z) + bf_lo(pb.z), 0.0f), w2b.x, acc);
    acc = fmaf(fmaxf(bf_hi(pa.z) + bf_hi(pb.z), 0.0f), w2b.y, acc);
    acc = fmaf(fmaxf(bf_lo(pa.w) + bf_lo(pb.w), 0.0f), w2b.z, acc);
    acc = fmaf(fmaxf(bf_hi(pa.w) + bf_hi(pb.w), 0.0f), w2b.w, acc);
    acc += __shfl_xor(acc, 8);
    acc += __shfl_xor(acc, 4);
    acc += __shfl_xor(acc, 2);
    acc += __shfl_xor(acc, 1);
    if (t == 0 && valid) out[e] = 1.0f / (1.0f + __expf(-(acc + b2s)));
  }
}

extern "C" void kernel_launch(void* const* d_in, const int* in_sizes, int n_in,
                              void* d_out, int out_size, void* d_ws, size_t ws_size,
                              hipStream_t stream) {
  const int*   src = (const int*)d_in[0];
  const int*   dst = (const int*)d_in[1];
  const float* h   = (const float*)d_in[2];
  const float* W1  = (const float*)d_in[3];
  const float* b1  = (const float*)d_in[4];
  const float* W2  = (const float*)d_in[5];
  const float* b2  = (const float*)d_in[6];
  float* out = (float*)d_out;
  const int nE = in_sizes[0];
  const int nN = in_sizes[2] / IN_FEATS;
  const int nTiles = (nN + TILE_M - 1) / TILE_M;

  ushort* P = (ushort*)d_ws;                      // nN*512 B  (~51.2MB)

  hipLaunchKernelGGL(gemm_pipe_kernel, dim3(GEMM_BLOCKS), dim3(1024), 0, stream, h, W1, b1, P, nN, nTiles);
  hipLaunchKernelGGL(edge_kernel, dim3(4096), dim3(256), 0, stream, src, dst, P, W2, b2, out, nE);
}